// Round 11
// baseline (179.877 us; speedup 1.0000x reference)
//
#include <hip/hip_runtime.h>
#include <hip/hip_bf16.h>

typedef __attribute__((ext_vector_type(8))) short bf16x8;
typedef __attribute__((ext_vector_type(4))) float f32x4;

#define NB 2048
#define TT 128   // T-1
#define FF 128
#define HH 128
#define NG 512   // 4*H

__device__ __forceinline__ unsigned short f2bf(float x) {
  union { float f; unsigned u; } v; v.f = x;
  unsigned r = (v.u + 0x7fffu + ((v.u >> 16) & 1u)) >> 16;
  return (unsigned short)r;
}
__device__ __forceinline__ unsigned cvtpk_bf16(float lo, float hi) {
  unsigned r;
  asm("v_cvt_pk_bf16_f32 %0, %1, %2" : "=v"(r) : "v"(lo), "v"(hi));
  return r;
}
__device__ __forceinline__ float frcp(float x) { return __builtin_amdgcn_rcpf(x); }
__device__ __forceinline__ float sigf(float x) { return frcp(1.f + __expf(-x)); }
__device__ __forceinline__ float tanh_(float x) {
  float e = __expf(-2.f * x);
  return (1.f - e) * frcp(1.f + e);
}
// XOR swizzle for 256B (128 bf16) rows: spreads 16B chunks across banks
__device__ __forceinline__ unsigned swzb(int row, int kbyte) {
  return (unsigned)(row * 256 + (kbyte ^ ((row & 7) << 4)));
}
// barrier that does NOT drain vmcnt; single asm so no memory op crosses,
// but register-only VALU may be scheduled across it.
__device__ __forceinline__ void barrier_lds() {
  asm volatile("s_waitcnt lgkmcnt(0)\n\ts_barrier" ::: "memory");
}

// ------- K0: prep (w_ih, w_hh -> bf16; bias = b_ih + b_hh) -------------------
__global__ void k_prep(const float* __restrict__ w_ih, const float* __restrict__ w_hh,
                       const float* __restrict__ b_ih, const float* __restrict__ b_hh,
                       unsigned short* __restrict__ wihb, unsigned short* __restrict__ whhb,
                       float* __restrict__ bias) {
  int g = blockIdx.x * blockDim.x + threadIdx.x;
  int gs = gridDim.x * blockDim.x;
  for (int i = g; i < NG * FF; i += gs) {
    wihb[i] = f2bf(w_ih[i]);
    whhb[i] = f2bf(w_hh[i]);
  }
  if (g < NG) bias[g] = b_ih[g] + b_hh[g];
}

// -------- K1: FUSED attention + recurrence -----------------------------------
// Prologue: wave w streams row w with float4 loads (lane l -> f4=l&31,
// t-parity l>>5; 64 x 1KB wave-loads, 4 acc chains), shfl softmax, 4KB LDS
// bounce redistributes a to the (srow,sf) float2 layout. Loop: prefetched x(t)
// (L3-hot) is multiplied by a on the fly, written to d_out and packed to xLds.
// K=256 MFMA ([h | xa] @ [w_hh | w_ih]^T); h-MFMA first; x-MFMA in the
// pointwise shadow; stage-write deferred one body.
__global__ __launch_bounds__(512, 1) void k_rnn_fused(const unsigned short* __restrict__ whhb,
                                                      const unsigned short* __restrict__ wihb,
                                                      const float* __restrict__ bias,
                                                      const float* __restrict__ x,
                                                      const float* __restrict__ w_lin,
                                                      float* __restrict__ xaout_base,
                                                      float* __restrict__ enc) {
  __shared__ unsigned char hLds[2][2048];  // 8 rows x 128 bf16
  __shared__ unsigned char xLds[2][2048];
  __shared__ float wxs[TT];
  __shared__ float aRow[8][FF];
  int tid = threadIdx.x;
  int l = tid & 63, w = tid >> 6;
  int lg = l >> 4;
  bool low = (lg < 2);
  int b0 = blockIdx.x * 8;
  int kl = w * 16 + (l & 15);  // gate column k in [0,128)
  int ar = l & 7;              // LDS row this lane reads (broadcast for l&8)

  // B-fragments: per gate g, ks 0..3 = w_hh (K=h), ks 4..7 = w_ih (K=xa)
  bf16x8 Bf[4][8];
  f32x4 bv0, bv1, bv2, bv3;
  {
    float bc0 = bias[0 * 128 + kl], bc1 = bias[1 * 128 + kl];
    float bc2 = bias[2 * 128 + kl], bc3 = bias[3 * 128 + kl];
    bv0 = (f32x4){bc0, bc0, bc0, bc0};
    bv1 = (f32x4){bc1, bc1, bc1, bc1};
    bv2 = (f32x4){bc2, bc2, bc2, bc2};
    bv3 = (f32x4){bc3, bc3, bc3, bc3};
  }
#pragma unroll
  for (int g = 0; g < 4; ++g) {
    int n = g * 128 + kl;
#pragma unroll
    for (int ks = 0; ks < 4; ++ks) {
      Bf[g][ks]     = *(const bf16x8*)(whhb + (size_t)n * HH + ks * 32 + lg * 8);
      Bf[g][4 + ks] = *(const bf16x8*)(wihb + (size_t)n * FF + ks * 32 + lg * 8);
    }
  }
  if (tid < TT) wxs[tid] = w_lin[2 * HH + tid];
  // zero h double-buffer (h(0) = 0)
  ((unsigned*)hLds)[tid] = 0u;
  ((unsigned*)hLds)[tid + 512] = 0u;
  __syncthreads();

  // ---- attention s_x: cooperative float4 streaming (wave w = row w) ----
  {
    int f4 = l & 31, tpar = l >> 5;
    const float4* xb4 = (const float4*)(x + (size_t)(b0 + w) * TT * FF);
    float4 ac0 = {0,0,0,0}, ac1 = {0,0,0,0}, ac2 = {0,0,0,0}, ac3 = {0,0,0,0};
#pragma unroll 4
    for (int j = 0; j < 64; j += 4) {
      float4 va = xb4[(tpar + 2 * (j + 0)) * 32 + f4]; float wa = wxs[tpar + 2 * (j + 0)];
      float4 vb = xb4[(tpar + 2 * (j + 1)) * 32 + f4]; float wb = wxs[tpar + 2 * (j + 1)];
      float4 vc = xb4[(tpar + 2 * (j + 2)) * 32 + f4]; float wc = wxs[tpar + 2 * (j + 2)];
      float4 vd = xb4[(tpar + 2 * (j + 3)) * 32 + f4]; float wd = wxs[tpar + 2 * (j + 3)];
      ac0.x += va.x * wa; ac0.y += va.y * wa; ac0.z += va.z * wa; ac0.w += va.w * wa;
      ac1.x += vb.x * wb; ac1.y += vb.y * wb; ac1.z += vb.z * wb; ac1.w += vb.w * wb;
      ac2.x += vc.x * wc; ac2.y += vc.y * wc; ac2.z += vc.z * wc; ac2.w += vc.w * wc;
      ac3.x += vd.x * wd; ac3.y += vd.y * wd; ac3.z += vd.z * wd; ac3.w += vd.w * wd;
    }
    float sx = ac0.x + ac1.x + ac2.x + ac3.x;
    float sy = ac0.y + ac1.y + ac2.y + ac3.y;
    float sz = ac0.z + ac1.z + ac2.z + ac3.z;
    float sw = ac0.w + ac1.w + ac2.w + ac3.w;
    // fold t-parities (lane l <-> l^32 hold complementary halves)
    sx += __shfl_xor(sx, 32); sy += __shfl_xor(sy, 32);
    sz += __shfl_xor(sz, 32); sw += __shfl_xor(sw, 32);
    // softmax over the 128 f's (32 lanes x 4 each; lanes 32-63 are dups)
    float m = fmaxf(fmaxf(sx, sy), fmaxf(sz, sw));
#pragma unroll
    for (int d = 1; d < 32; d <<= 1) m = fmaxf(m, __shfl_xor(m, d));
    float e0 = __expf(sx - m), e1 = __expf(sy - m);
    float e2 = __expf(sz - m), e3 = __expf(sw - m);
    float sum = e0 + e1 + e2 + e3;
#pragma unroll
    for (int d = 1; d < 32; d <<= 1) sum += __shfl_xor(sum, d);
    float inv = frcp(sum);
    float4 av; av.x = e0 * inv; av.y = e1 * inv; av.z = e2 * inv; av.w = e3 * inv;
    *(float4*)(&aRow[w][f4 * 4]) = av;   // lanes 32-63 write same addr/value
  }
  barrier_lds();

  int srow = tid >> 6, sf = (tid & 63) * 2;
  const float* xrow = x + (size_t)(b0 + srow) * TT * FF + sf;
  float* xaout = xaout_base + (size_t)(b0 + srow) * TT * FF + sf;
  float a0 = aRow[srow][sf], a1 = aRow[srow][sf + 1];

  // ---- stage xa(0)->xLds[0], xa(1)->xLds[1]; write xa(0),xa(1); pv = x(2) ----
  float2 v0p = *(const float2*)(xrow);            // L3/L2-hot re-reads
  float2 v1p = *(const float2*)(xrow + FF);
  float2 pv  = *(const float2*)(xrow + 2 * FF);
  float xa00 = v0p.x * a0, xa01 = v0p.y * a1;
  float xa10 = v1p.x * a0, xa11 = v1p.y * a1;
  *(float2*)(xaout)      = (float2){xa00, xa01};
  *(float2*)(xaout + FF) = (float2){xa10, xa11};
  *(unsigned*)(xLds[0] + swzb(srow, sf * 2)) = cvtpk_bf16(xa00, xa01);
  *(unsigned*)(xLds[1] + swzb(srow, sf * 2)) = cvtpk_bf16(xa10, xa11);
  barrier_lds();

  // xaccA = bias + x-gates(0)
  f32x4 xaccA0, xaccA1, xaccA2, xaccA3;
  f32x4 xaccB0, xaccB1, xaccB2, xaccB3;
  {
    bf16x8 Ax[4];
#pragma unroll
    for (int ks = 0; ks < 4; ++ks)
      Ax[ks] = *(const bf16x8*)(xLds[0] + swzb(ar, ks * 64 + lg * 16));
    xaccA0 = bv0; xaccA1 = bv1; xaccA2 = bv2; xaccA3 = bv3;
#pragma unroll
    for (int ks = 0; ks < 4; ++ks) {
      xaccA0 = __builtin_amdgcn_mfma_f32_16x16x32_bf16(Ax[ks], Bf[0][4 + ks], xaccA0, 0, 0, 0);
      xaccA1 = __builtin_amdgcn_mfma_f32_16x16x32_bf16(Ax[ks], Bf[1][4 + ks], xaccA1, 0, 0, 0);
      xaccA2 = __builtin_amdgcn_mfma_f32_16x16x32_bf16(Ax[ks], Bf[2][4 + ks], xaccA2, 0, 0, 0);
      xaccA3 = __builtin_amdgcn_mfma_f32_16x16x32_bf16(Ax[ks], Bf[3][4 + ks], xaccA3, 0, 0, 0);
    }
  }
  barrier_lds();

  int bq0 = ((lg & 1) << 2) | ((lg >> 1) << 1);  // 0,4,2,6
  float c0 = 0.f, c1 = 0.f;
  float* pA = enc + (size_t)(b0 + bq0) * TT * HH + kl;
  float* pB = enc + (size_t)(b0 + bq0 + 1) * TT * HH + kl;

#define RNN_BODY(tc, CUR, NXT, XU0, XU1, XU2, XU3, XN0, XN1, XN2, XN3)          \
  {                                                                              \
    /* pv holds raw x(tc+2): apply attention, emit xa output, stage to LDS */    \
    float xv0 = pv.x * a0, xv1 = pv.y * a1;                                      \
    *(unsigned*)(xLds[CUR] + swzb(srow, sf * 2)) = cvtpk_bf16(xv0, xv1);         \
    if ((tc) + 2 < TT) *(float2*)(xaout + (size_t)((tc) + 2) * FF) = (float2){xv0, xv1}; \
    int tnx = ((tc) + 3 < TT) ? (tc) + 3 : TT - 1;                               \
    pv = *(const float2*)(xrow + (size_t)tnx * FF);                              \
    bf16x8 Ah[4], Ax[4];                                                         \
    _Pragma("unroll")                                                            \
    for (int ks = 0; ks < 4; ++ks)                                               \
      Ah[ks] = *(const bf16x8*)(hLds[CUR] + swzb(ar, ks * 64 + lg * 16));        \
    _Pragma("unroll")                                                            \
    for (int ks = 0; ks < 4; ++ks)                                               \
      Ax[ks] = *(const bf16x8*)(xLds[NXT] + swzb(ar, ks * 64 + lg * 16));        \
    /* h-chain first: accumulates onto (bias + x-gates) from prev step */        \
    f32x4 s0_ = XU0, s1_ = XU1, s2_ = XU2, s3_ = XU3;                            \
    _Pragma("unroll")                                                            \
    for (int ks = 0; ks < 4; ++ks) {                                             \
      s0_ = __builtin_amdgcn_mfma_f32_16x16x32_bf16(Ah[ks], Bf[0][ks], s0_, 0,0,0);\
      s1_ = __builtin_amdgcn_mfma_f32_16x16x32_bf16(Ah[ks], Bf[1][ks], s1_, 0,0,0);\
      s2_ = __builtin_amdgcn_mfma_f32_16x16x32_bf16(Ah[ks], Bf[2][ks], s2_, 0,0,0);\
      s3_ = __builtin_amdgcn_mfma_f32_16x16x32_bf16(Ah[ks], Bf[3][ks], s3_, 0,0,0);\
    }                                                                            \
    /* x-chain (independent): issues in the shadow of the pointwise below */     \
    XN0 = bv0; XN1 = bv1; XN2 = bv2; XN3 = bv3;                                  \
    _Pragma("unroll")                                                            \
    for (int ks = 0; ks < 4; ++ks) {                                             \
      XN0 = __builtin_amdgcn_mfma_f32_16x16x32_bf16(Ax[ks], Bf[0][4+ks], XN0, 0,0,0);\
      XN1 = __builtin_amdgcn_mfma_f32_16x16x32_bf16(Ax[ks], Bf[1][4+ks], XN1, 0,0,0);\
      XN2 = __builtin_amdgcn_mfma_f32_16x16x32_bf16(Ax[ks], Bf[2][4+ks], XN2, 0,0,0);\
      XN3 = __builtin_amdgcn_mfma_f32_16x16x32_bf16(Ax[ks], Bf[3][4+ks], XN3, 0,0,0);\
    }                                                                            \
    float giA = low ? s0_[0] : s0_[2], giB = low ? s0_[1] : s0_[3];              \
    float gfA = low ? s1_[0] : s1_[2], gfB = low ? s1_[1] : s1_[3];              \
    float ggA = low ? s2_[0] : s2_[2], ggB = low ? s2_[1] : s2_[3];              \
    float goA = low ? s3_[0] : s3_[2], goB = low ? s3_[1] : s3_[3];              \
    float cnA = sigf(gfA) * c0 + sigf(giA) * tanh_(ggA);                         \
    float cnB = sigf(gfB) * c1 + sigf(giB) * tanh_(ggB);                         \
    c0 = cnA; c1 = cnB;                                                          \
    float hvA = sigf(goA) * tanh_(cnA);                                          \
    float hvB = sigf(goB) * tanh_(cnB);                                          \
    unsigned hp = cvtpk_bf16(hvA, hvB);                                          \
    unsigned hq = hp >> 16;                                                      \
    *(unsigned short*)(hLds[NXT] + swzb(bq0, kl * 2)) = (unsigned short)hp;      \
    *(unsigned short*)(hLds[NXT] + swzb(bq0 + 1, kl * 2)) = (unsigned short)hq;  \
    pA[(size_t)(tc) * HH] = hvA;                                                 \
    pB[(size_t)(tc) * HH] = hvB;                                                 \
    barrier_lds();                                                               \
  }

  for (int t = 0; t < TT; t += 2) {
    RNN_BODY(t,     0, 1, xaccA0, xaccA1, xaccA2, xaccA3, xaccB0, xaccB1, xaccB2, xaccB3)
    RNN_BODY(t + 1, 1, 0, xaccB0, xaccB1, xaccB2, xaccB3, xaccA0, xaccA1, xaccA2, xaccA3)
  }
#undef RNN_BODY
}

extern "C" void kernel_launch(void* const* d_in, const int* in_sizes, int n_in,
                              void* d_out, int out_size, void* d_ws, size_t ws_size,
                              hipStream_t stream) {
  (void)in_sizes; (void)n_in; (void)out_size; (void)ws_size;
  const float* x     = (const float*)d_in[0];
  const float* w_lin = (const float*)d_in[1];
  const float* w_ih  = (const float*)d_in[3];
  const float* w_hh  = (const float*)d_in[4];
  const float* b_ih  = (const float*)d_in[5];
  const float* b_hh  = (const float*)d_in[6];
  float* out = (float*)d_out;  // [x_atn | x_enc] f32

  char* ws = (char*)d_ws;
  float* bias          = (float*)ws;                                 // 2 KB
  unsigned short* wihb = (unsigned short*)(ws + 4096);               // 128 KB
  unsigned short* whhb = (unsigned short*)(ws + 4096 + (1 << 17));   // 128 KB

  float* enc = out + (size_t)NB * TT * FF;

  k_prep<<<dim3(64), dim3(256), 0, stream>>>(w_ih, w_hh, b_ih, b_hh, wihb, whhb, bias);
  k_rnn_fused<<<dim3(256), dim3(512), 0, stream>>>(whhb, wihb, bias, x, w_lin, out, enc);
}

// Round 12
// 156.939 us; speedup vs baseline: 1.1462x; 1.1462x over previous
//
#include <hip/hip_runtime.h>
#include <hip/hip_bf16.h>

typedef __attribute__((ext_vector_type(8))) short bf16x8;
typedef __attribute__((ext_vector_type(4))) float f32x4;

#define NB 2048
#define TT 128   // T-1
#define FF 128
#define HH 128
#define NG 512   // 4*H

__device__ __forceinline__ unsigned short f2bf(float x) {
  union { float f; unsigned u; } v; v.f = x;
  unsigned r = (v.u + 0x7fffu + ((v.u >> 16) & 1u)) >> 16;
  return (unsigned short)r;
}
__device__ __forceinline__ unsigned cvtpk_bf16(float lo, float hi) {
  unsigned r;
  asm("v_cvt_pk_bf16_f32 %0, %1, %2" : "=v"(r) : "v"(lo), "v"(hi));
  return r;
}
__device__ __forceinline__ float frcp(float x) { return __builtin_amdgcn_rcpf(x); }
__device__ __forceinline__ float sigf(float x) { return frcp(1.f + __expf(-x)); }
__device__ __forceinline__ float tanh_(float x) {
  float e = __expf(-2.f * x);
  return (1.f - e) * frcp(1.f + e);
}
// XOR swizzle for 256B (128 bf16) rows: spreads 16B chunks across banks
__device__ __forceinline__ unsigned swzb(int row, int kbyte) {
  return (unsigned)(row * 256 + (kbyte ^ ((row & 7) << 4)));
}
// barrier that does NOT drain vmcnt; single asm so no memory op crosses,
// but register-only VALU may be scheduled across it.
__device__ __forceinline__ void barrier_lds() {
  asm volatile("s_waitcnt lgkmcnt(0)\n\ts_barrier" ::: "memory");
}

// ------- K0: prep (w_ih, w_hh -> bf16; bias = b_ih + b_hh) -------------------
__global__ void k_prep(const float* __restrict__ w_ih, const float* __restrict__ w_hh,
                       const float* __restrict__ b_ih, const float* __restrict__ b_hh,
                       unsigned short* __restrict__ wihb, unsigned short* __restrict__ whhb,
                       float* __restrict__ bias) {
  int g = blockIdx.x * blockDim.x + threadIdx.x;
  int gs = gridDim.x * blockDim.x;
  for (int i = g; i < NG * FF; i += gs) {
    wihb[i] = f2bf(w_ih[i]);
    whhb[i] = f2bf(w_hh[i]);
  }
  if (g < NG) bias[g] = b_ih[g] + b_hh[g];
}

// -------- K1: FUSED attention + recurrence -----------------------------------
// Prologue FIRST with the whole register file (weights loaded after it):
// wave w streams row w with float4 loads, 8 acc chains, shfl softmax, 4KB LDS
// bounce. Then Bf/bv weight fragments load (L2-hot), xa(0..2) re-read from L3.
// Loop: K=256 MFMA ([h | xa] @ [w_hh | w_ih]^T); h-MFMA first; x-MFMA in the
// pointwise shadow; stage-write deferred one body.
__global__ __launch_bounds__(512, 1) void k_rnn_fused(const unsigned short* __restrict__ whhb,
                                                      const unsigned short* __restrict__ wihb,
                                                      const float* __restrict__ bias,
                                                      const float* __restrict__ x,
                                                      const float* __restrict__ w_lin,
                                                      float* __restrict__ xaout_base,
                                                      float* __restrict__ enc) {
  __shared__ unsigned char hLds[2][2048];  // 8 rows x 128 bf16
  __shared__ unsigned char xLds[2][2048];
  __shared__ float wxs[TT];
  __shared__ float aRow[8][FF];
  int tid = threadIdx.x;
  int l = tid & 63, w = tid >> 6;
  int lg = l >> 4;
  bool low = (lg < 2);
  int b0 = blockIdx.x * 8;
  int kl = w * 16 + (l & 15);  // gate column k in [0,128)
  int ar = l & 7;              // LDS row this lane reads (broadcast for l&8)

  if (tid < TT) wxs[tid] = w_lin[2 * HH + tid];
  // zero h double-buffer (h(0) = 0)
  ((unsigned*)hLds)[tid] = 0u;
  ((unsigned*)hLds)[tid + 512] = 0u;
  __syncthreads();

  // ---- attention s_x: cooperative float4 streaming (wave w = row w) ----
  // NOTE: runs BEFORE any weight-fragment load -> full VGPR budget, deep MLP.
  {
    int f4 = l & 31, tpar = l >> 5;
    const float4* xb4 = (const float4*)(x + (size_t)(b0 + w) * TT * FF);
    float4 acc[8];
#pragma unroll
    for (int u = 0; u < 8; ++u) acc[u] = (float4){0.f, 0.f, 0.f, 0.f};
#pragma unroll
    for (int j = 0; j < 64; j += 8) {
      float4 v[8];
#pragma unroll
      for (int u = 0; u < 8; ++u) v[u] = xb4[(tpar + 2 * (j + u)) * 32 + f4];
#pragma unroll
      for (int u = 0; u < 8; ++u) {
        float wt = wxs[tpar + 2 * (j + u)];
        acc[u].x += v[u].x * wt; acc[u].y += v[u].y * wt;
        acc[u].z += v[u].z * wt; acc[u].w += v[u].w * wt;
      }
    }
#pragma unroll
    for (int u = 4; u < 8; ++u) {
      acc[u - 4].x += acc[u].x; acc[u - 4].y += acc[u].y;
      acc[u - 4].z += acc[u].z; acc[u - 4].w += acc[u].w;
    }
    float sx = acc[0].x + acc[1].x + acc[2].x + acc[3].x;
    float sy = acc[0].y + acc[1].y + acc[2].y + acc[3].y;
    float sz = acc[0].z + acc[1].z + acc[2].z + acc[3].z;
    float sw = acc[0].w + acc[1].w + acc[2].w + acc[3].w;
    // fold t-parities (lane l <-> l^32 hold complementary halves)
    sx += __shfl_xor(sx, 32); sy += __shfl_xor(sy, 32);
    sz += __shfl_xor(sz, 32); sw += __shfl_xor(sw, 32);
    // softmax over the 128 f's (32 lanes x 4 each; lanes 32-63 are dups)
    float m = fmaxf(fmaxf(sx, sy), fmaxf(sz, sw));
#pragma unroll
    for (int d = 1; d < 32; d <<= 1) m = fmaxf(m, __shfl_xor(m, d));
    float e0 = __expf(sx - m), e1 = __expf(sy - m);
    float e2 = __expf(sz - m), e3 = __expf(sw - m);
    float sum = e0 + e1 + e2 + e3;
#pragma unroll
    for (int d = 1; d < 32; d <<= 1) sum += __shfl_xor(sum, d);
    float inv = frcp(sum);
    float4 av; av.x = e0 * inv; av.y = e1 * inv; av.z = e2 * inv; av.w = e3 * inv;
    if (l < 32) *(float4*)(&aRow[w][f4 * 4]) = av;
  }
  barrier_lds();

  // ---- weight fragments (loaded only now; cannot hoist above the barrier) ---
  bf16x8 Bf[4][8];
  f32x4 bv0, bv1, bv2, bv3;
  {
    float bc0 = bias[0 * 128 + kl], bc1 = bias[1 * 128 + kl];
    float bc2 = bias[2 * 128 + kl], bc3 = bias[3 * 128 + kl];
    bv0 = (f32x4){bc0, bc0, bc0, bc0};
    bv1 = (f32x4){bc1, bc1, bc1, bc1};
    bv2 = (f32x4){bc2, bc2, bc2, bc2};
    bv3 = (f32x4){bc3, bc3, bc3, bc3};
  }
#pragma unroll
  for (int g = 0; g < 4; ++g) {
    int n = g * 128 + kl;
#pragma unroll
    for (int ks = 0; ks < 4; ++ks) {
      Bf[g][ks]     = *(const bf16x8*)(whhb + (size_t)n * HH + ks * 32 + lg * 8);
      Bf[g][4 + ks] = *(const bf16x8*)(wihb + (size_t)n * FF + ks * 32 + lg * 8);
    }
  }

  int srow = tid >> 6, sf = (tid & 63) * 2;
  const float* xrow = x + (size_t)(b0 + srow) * TT * FF + sf;
  float* xaout = xaout_base + (size_t)(b0 + srow) * TT * FF + sf;
  float a0 = aRow[srow][sf], a1 = aRow[srow][sf + 1];

  // ---- stage xa(0)->xLds[0], xa(1)->xLds[1]; write xa(0),xa(1); pv = x(2) ----
  float2 v0p = *(const float2*)(xrow);            // L3/L2-hot re-reads
  float2 v1p = *(const float2*)(xrow + FF);
  float2 pv  = *(const float2*)(xrow + 2 * FF);
  float xa00 = v0p.x * a0, xa01 = v0p.y * a1;
  float xa10 = v1p.x * a0, xa11 = v1p.y * a1;
  *(float2*)(xaout)      = (float2){xa00, xa01};
  *(float2*)(xaout + FF) = (float2){xa10, xa11};
  *(unsigned*)(xLds[0] + swzb(srow, sf * 2)) = cvtpk_bf16(xa00, xa01);
  *(unsigned*)(xLds[1] + swzb(srow, sf * 2)) = cvtpk_bf16(xa10, xa11);
  barrier_lds();

  // xaccA = bias + x-gates(0)
  f32x4 xaccA0, xaccA1, xaccA2, xaccA3;
  f32x4 xaccB0, xaccB1, xaccB2, xaccB3;
  {
    bf16x8 Ax[4];
#pragma unroll
    for (int ks = 0; ks < 4; ++ks)
      Ax[ks] = *(const bf16x8*)(xLds[0] + swzb(ar, ks * 64 + lg * 16));
    xaccA0 = bv0; xaccA1 = bv1; xaccA2 = bv2; xaccA3 = bv3;
#pragma unroll
    for (int ks = 0; ks < 4; ++ks) {
      xaccA0 = __builtin_amdgcn_mfma_f32_16x16x32_bf16(Ax[ks], Bf[0][4 + ks], xaccA0, 0, 0, 0);
      xaccA1 = __builtin_amdgcn_mfma_f32_16x16x32_bf16(Ax[ks], Bf[1][4 + ks], xaccA1, 0, 0, 0);
      xaccA2 = __builtin_amdgcn_mfma_f32_16x16x32_bf16(Ax[ks], Bf[2][4 + ks], xaccA2, 0, 0, 0);
      xaccA3 = __builtin_amdgcn_mfma_f32_16x16x32_bf16(Ax[ks], Bf[3][4 + ks], xaccA3, 0, 0, 0);
    }
  }
  barrier_lds();

  int bq0 = ((lg & 1) << 2) | ((lg >> 1) << 1);  // 0,4,2,6
  float c0 = 0.f, c1 = 0.f;
  float* pA = enc + (size_t)(b0 + bq0) * TT * HH + kl;
  float* pB = enc + (size_t)(b0 + bq0 + 1) * TT * HH + kl;

#define RNN_BODY(tc, CUR, NXT, XU0, XU1, XU2, XU3, XN0, XN1, XN2, XN3)          \
  {                                                                              \
    /* pv holds raw x(tc+2): apply attention, emit xa output, stage to LDS */    \
    float xv0 = pv.x * a0, xv1 = pv.y * a1;                                      \
    *(unsigned*)(xLds[CUR] + swzb(srow, sf * 2)) = cvtpk_bf16(xv0, xv1);         \
    if ((tc) + 2 < TT) *(float2*)(xaout + (size_t)((tc) + 2) * FF) = (float2){xv0, xv1}; \
    int tnx = ((tc) + 3 < TT) ? (tc) + 3 : TT - 1;                               \
    pv = *(const float2*)(xrow + (size_t)tnx * FF);                              \
    bf16x8 Ah[4], Ax[4];                                                         \
    _Pragma("unroll")                                                            \
    for (int ks = 0; ks < 4; ++ks)                                               \
      Ah[ks] = *(const bf16x8*)(hLds[CUR] + swzb(ar, ks * 64 + lg * 16));        \
    _Pragma("unroll")                                                            \
    for (int ks = 0; ks < 4; ++ks)                                               \
      Ax[ks] = *(const bf16x8*)(xLds[NXT] + swzb(ar, ks * 64 + lg * 16));        \
    /* h-chain first: accumulates onto (bias + x-gates) from prev step */        \
    f32x4 s0_ = XU0, s1_ = XU1, s2_ = XU2, s3_ = XU3;                            \
    _Pragma("unroll")                                                            \
    for (int ks = 0; ks < 4; ++ks) {                                             \
      s0_ = __builtin_amdgcn_mfma_f32_16x16x32_bf16(Ah[ks], Bf[0][ks], s0_, 0,0,0);\
      s1_ = __builtin_amdgcn_mfma_f32_16x16x32_bf16(Ah[ks], Bf[1][ks], s1_, 0,0,0);\
      s2_ = __builtin_amdgcn_mfma_f32_16x16x32_bf16(Ah[ks], Bf[2][ks], s2_, 0,0,0);\
      s3_ = __builtin_amdgcn_mfma_f32_16x16x32_bf16(Ah[ks], Bf[3][ks], s3_, 0,0,0);\
    }                                                                            \
    /* x-chain (independent): issues in the shadow of the pointwise below */     \
    XN0 = bv0; XN1 = bv1; XN2 = bv2; XN3 = bv3;                                  \
    _Pragma("unroll")                                                            \
    for (int ks = 0; ks < 4; ++ks) {                                             \
      XN0 = __builtin_amdgcn_mfma_f32_16x16x32_bf16(Ax[ks], Bf[0][4+ks], XN0, 0,0,0);\
      XN1 = __builtin_amdgcn_mfma_f32_16x16x32_bf16(Ax[ks], Bf[1][4+ks], XN1, 0,0,0);\
      XN2 = __builtin_amdgcn_mfma_f32_16x16x32_bf16(Ax[ks], Bf[2][4+ks], XN2, 0,0,0);\
      XN3 = __builtin_amdgcn_mfma_f32_16x16x32_bf16(Ax[ks], Bf[3][4+ks], XN3, 0,0,0);\
    }                                                                            \
    float giA = low ? s0_[0] : s0_[2], giB = low ? s0_[1] : s0_[3];              \
    float gfA = low ? s1_[0] : s1_[2], gfB = low ? s1_[1] : s1_[3];              \
    float ggA = low ? s2_[0] : s2_[2], ggB = low ? s2_[1] : s2_[3];              \
    float goA = low ? s3_[0] : s3_[2], goB = low ? s3_[1] : s3_[3];              \
    float cnA = sigf(gfA) * c0 + sigf(giA) * tanh_(ggA);                         \
    float cnB = sigf(gfB) * c1 + sigf(giB) * tanh_(ggB);                         \
    c0 = cnA; c1 = cnB;                                                          \
    float hvA = sigf(goA) * tanh_(cnA);                                          \
    float hvB = sigf(goB) * tanh_(cnB);                                          \
    unsigned hp = cvtpk_bf16(hvA, hvB);                                          \
    unsigned hq = hp >> 16;                                                      \
    *(unsigned short*)(hLds[NXT] + swzb(bq0, kl * 2)) = (unsigned short)hp;      \
    *(unsigned short*)(hLds[NXT] + swzb(bq0 + 1, kl * 2)) = (unsigned short)hq;  \
    pA[(size_t)(tc) * HH] = hvA;                                                 \
    pB[(size_t)(tc) * HH] = hvB;                                                 \
    barrier_lds();                                                               \
  }

  for (int t = 0; t < TT; t += 2) {
    RNN_BODY(t,     0, 1, xaccA0, xaccA1, xaccA2, xaccA3, xaccB0, xaccB1, xaccB2, xaccB3)
    RNN_BODY(t + 1, 1, 0, xaccB0, xaccB1, xaccB2, xaccB3, xaccA0, xaccA1, xaccA2, xaccA3)
  }
#undef RNN_BODY
}

extern "C" void kernel_launch(void* const* d_in, const int* in_sizes, int n_in,
                              void* d_out, int out_size, void* d_ws, size_t ws_size,
                              hipStream_t stream) {
  (void)in_sizes; (void)n_in; (void)out_size; (void)ws_size;
  const float* x     = (const float*)d_in[0];
  const float* w_lin = (const float*)d_in[1];
  const float* w_ih  = (const float*)d_in[3];
  const float* w_hh  = (const float*)d_in[4];
  const float* b_ih  = (const float*)d_in[5];
  const float* b_hh  = (const float*)d_in[6];
  float* out = (float*)d_out;  // [x_atn | x_enc] f32

  char* ws = (char*)d_ws;
  float* bias          = (float*)ws;                                 // 2 KB
  unsigned short* wihb = (unsigned short*)(ws + 4096);               // 128 KB
  unsigned short* whhb = (unsigned short*)(ws + 4096 + (1 << 17));   // 128 KB

  float* enc = out + (size_t)NB * TT * FF;

  k_prep<<<dim3(64), dim3(256), 0, stream>>>(w_ih, w_hh, b_ih, b_hh, wihb, whhb, bias);
  k_rnn_fused<<<dim3(256), dim3(512), 0, stream>>>(whhb, wihb, bias, x, w_lin, out, enc);
}